// Round 7
// baseline (618.061 us; speedup 1.0000x reference)
//
#include <hip/hip_runtime.h>
#include <hip/hip_bf16.h>

#define NN 100000
#define EE 1600000
#define HID 128
#define NEG 0.2f
#define CAP 64     // fixed CSR capacity per node (avg deg 16, P(deg>64) ~ 1e-19)
#define BSH 9      // coarse bucket = dst >> 9 (512 nodes/bucket)
#define NB 196     // ceil(NN / 512)
#define CAPB 9216  // per-bucket edge capacity (mean 8192, sigma~90 -> 11 sigma)
#define EBLK 4096  // edges per k_bin block (782 blocks -> ~12 waves/CU)

typedef __attribute__((ext_vector_type(8))) short short8;
typedef __attribute__((ext_vector_type(4))) float f32x4;

// ---------------- projection GEMM via MFMA: xph = bf16(x @ proj_w + b) --------
#define PWS 264    // wT LDS stride in bf16 elems (528 B, 16B-aligned rows)
#define PNT ((NN + 15) / 16)   // 6250 row-tiles

__global__ __launch_bounds__(256) void k_proj(const float* __restrict__ x,
    const float* __restrict__ w, const float* __restrict__ bias,
    __hip_bfloat16* __restrict__ xph) {
  __shared__ short wT[128 * PWS];   // w^T as bf16, [n][k]
  const int tid = threadIdx.x;
  for (int l = tid; l < 256 * 128; l += 256) {
    int k = l >> 7, n = l & 127;
    __hip_bfloat16 bv = __float2bfloat16(w[l]);
    wT[n * PWS + k] = *(short*)&bv;
  }
  const int lane = tid & 63, wave = tid >> 6;
  const int rowgrp = lane >> 4, lcol = lane & 15;
  float bv[8];
#pragma unroll
  for (int ct = 0; ct < 8; ct++) bv[ct] = bias[ct * 16 + lcol];
  __syncthreads();
  for (int tile = blockIdx.x * 4 + wave; tile < PNT; tile += gridDim.x * 4) {
    const int r0 = tile * 16;
    int row = r0 + lcol;
    if (row >= NN) row = NN - 1;   // clamped load; stores guarded below
    const float* xr = x + (size_t)row * 256 + rowgrp * 8;
    short8 af[8];
#pragma unroll
    for (int kc = 0; kc < 8; kc++) {
      float4 u0 = *(const float4*)(xr + kc * 32);
      float4 u1 = *(const float4*)(xr + kc * 32 + 4);
      union { short8 v; __hip_bfloat162 h[4]; } u;
      u.h[0] = __float22bfloat162_rn(make_float2(u0.x, u0.y));
      u.h[1] = __float22bfloat162_rn(make_float2(u0.z, u0.w));
      u.h[2] = __float22bfloat162_rn(make_float2(u1.x, u1.y));
      u.h[3] = __float22bfloat162_rn(make_float2(u1.z, u1.w));
      af[kc] = u.v;
    }
#pragma unroll
    for (int ct = 0; ct < 8; ct++) {
      f32x4 acc = {0.f, 0.f, 0.f, 0.f};
#pragma unroll
      for (int kc = 0; kc < 8; kc++) {
        short8 bf = *(const short8*)&wT[(ct * 16 + lcol) * PWS + kc * 32 + rowgrp * 8];
        acc = __builtin_amdgcn_mfma_f32_16x16x32_bf16(af[kc], bf, acc, 0, 0, 0);
      }
#pragma unroll
      for (int r = 0; r < 4; r++) {
        int orow = r0 + rowgrp * 4 + r;   // C/D: row = (lane>>4)*4 + reg
        if (orow < NN) {
          __hip_bfloat16 ob = __float2bfloat16(acc[r] + bv[ct]);
          ((short*)xph)[(size_t)orow * 128 + ct * 16 + lcol] = *(short*)&ob;
        }
      }
    }
  }
}

// ---------------- per-node attention logits (bf16 xph) ----------------
__global__ __launch_bounds__(256) void k_alpha(const __hip_bfloat162* __restrict__ xph,
    const float* __restrict__ a0s, const float* __restrict__ a0d,
    const float* __restrict__ a1s, const float* __restrict__ a1d,
    float* __restrict__ as0, float* __restrict__ ad0,
    float* __restrict__ as1, float* __restrict__ ad1) {
  const int lane = threadIdx.x & 63;
  const int node = blockIdx.x * 4 + (threadIdx.x >> 6);
  if (node >= NN) return;
  float2 v = __bfloat1622float2(xph[(size_t)node * 64 + lane]);
  int i0 = 2 * lane;
  float p0 = v.x * a0s[i0] + v.y * a0s[i0 + 1];
  float p1 = v.x * a0d[i0] + v.y * a0d[i0 + 1];
  float p2 = v.x * a1s[i0] + v.y * a1s[i0 + 1];
  float p3 = v.x * a1d[i0] + v.y * a1d[i0 + 1];
#pragma unroll
  for (int off = 1; off < 8; off <<= 1) {
    p0 += __shfl_xor(p0, off, 64);
    p1 += __shfl_xor(p1, off, 64);
    p2 += __shfl_xor(p2, off, 64);
    p3 += __shfl_xor(p3, off, 64);
  }
  if ((lane & 7) == 0) {
    int h = lane >> 3;
    as0[node * 8 + h] = p0;
    ad0[node * 8 + h] = p1;
    as1[node * 8 + h] = p2;
    ad1[node * 8 + h] = p3;
  }
}

// ---------------- phase A: bin edges by coarse dst bucket ----------------
__global__ __launch_bounds__(256) void k_bin(const int* __restrict__ ei0,
    const int* __restrict__ ei1, int* __restrict__ gcur, int* __restrict__ binned) {
  const int p = blockIdx.y;
  const int* __restrict__ ei = p ? ei1 : ei0;
  const int* __restrict__ src = ei;
  const int* __restrict__ dst = ei + EE;
  int* __restrict__ gc = gcur + p * 256;
  int* __restrict__ bn = binned + (size_t)p * NB * CAPB;
  __shared__ int cntL[NB], baseL[NB], posL[NB];
  const int t = threadIdx.x;
  const int e0 = blockIdx.x * EBLK;
  const int e1 = min(e0 + EBLK, EE);
  for (int i = t; i < NB; i += 256) { cntL[i] = 0; posL[i] = 0; }
  __syncthreads();
  for (int e = e0 + t; e < e1; e += 256)
    atomicAdd(&cntL[dst[e] >> BSH], 1);
  __syncthreads();
  for (int i = t; i < NB; i += 256)
    baseL[i] = atomicAdd(&gc[i], cntL[i]);
  __syncthreads();
  for (int e = e0 + t; e < e1; e += 256) {
    int d = dst[e];
    int b = d >> BSH;
    int off = baseL[b] + atomicAdd(&posL[b], 1);
    if (off < CAPB) bn[b * CAPB + off] = (src[e] << BSH) | (d & 511);
  }
}

// ---------------- phase B: bucket -> fixed-capacity CSR ----------------
__global__ __launch_bounds__(512) void k_build(const int* __restrict__ gcur,
    const int* __restrict__ binned, int* __restrict__ cnt, int* __restrict__ csr) {
  const int p = blockIdx.y, b = blockIdx.x, t = threadIdx.x;
  const int* __restrict__ bn = binned + (size_t)p * NB * CAPB + (size_t)b * CAPB;
  const int n = min(gcur[p * 256 + b], CAPB);
  int* __restrict__ cs = csr + (size_t)p * NN * CAP;
  __shared__ int lc[512];
  lc[t] = 0;
  __syncthreads();
  const int node0 = b << BSH;
  for (int i = t; i < n; i += 512) {
    int v = bn[i];
    int ln = v & 511;
    int off = atomicAdd(&lc[ln], 1);
    if (off < CAP) cs[(size_t)(node0 + ln) * CAP + off] = v >> BSH;
  }
  __syncthreads();
  int n0 = node0 + t;
  if (n0 < NN) cnt[p * NN + n0] = lc[t];
}

// ---------------- GAT aggregation: 8-edge groups, one wave per dst node -------
// alpha phase: lane (g=lane>>3, h=lane&7) computes 64 DISTINCT alphas per
// group (8x amortization of the exp/LRELU chain vs per-edge duplication).
// feature phase: src broadcast via readlane-shfl, alpha via bpermute-shfl.
__global__ __launch_bounds__(256) void k_aggr(const __hip_bfloat162* __restrict__ xph,
    const float* __restrict__ as0, const float* __restrict__ ad0,
    const float* __restrict__ as1, const float* __restrict__ ad1,
    const int* __restrict__ cnt, const int* __restrict__ csr,
    __hip_bfloat162* __restrict__ h0, __hip_bfloat162* __restrict__ h1) {
  const int p = blockIdx.y;
  const int lane = threadIdx.x & 63;
  const int node = blockIdx.x * 4 + (threadIdx.x >> 6);
  if (node >= NN) return;
  const float* __restrict__ asrc = p ? as1 : as0;
  const float* __restrict__ adst = p ? ad1 : ad0;
  const int* __restrict__ cs = csr + ((size_t)p * NN + node) * CAP;
  __hip_bfloat162* __restrict__ hout = p ? h1 : h0;
  const int g = lane >> 3;       // alpha-phase edge slot
  const int h8 = lane & 7;       // alpha-phase head
  const int hf = lane >> 3;      // feature-phase head (bf162 elem 'lane' -> head lane>>3)
  const float ad8 = adst[(unsigned)node * 8u + h8];
  const int deg = min(cnt[p * NN + node], CAP);

  float dsum = 0.f, a0 = 0.f, a1 = 0.f;
  for (int e0 = 0; e0 < deg; e0 += 8) {
    int idx = e0 + g;
    bool valid = idx < deg;
    int s8 = cs[valid ? idx : 0];
    float t = asrc[(unsigned)s8 * 8u + h8];
    float xv = t + ad8;
    float al = __expf(fmaxf(xv, NEG * xv));   // leaky_relu = max(x, 0.2x)
    al = valid ? al : 0.f;
    dsum += al;
    const int nval = min(deg - e0, 8);
#pragma unroll
    for (int gp = 0; gp < 8; gp++) {
      if (gp >= nval) break;                      // wave-uniform
      int sb = __shfl(s8, gp * 8, 64);            // src of edge gp (readlane)
      float ab = __shfl(al, gp * 8 + hf, 64);     // alpha for my head (bpermute)
      float2 f = __bfloat1622float2(xph[(unsigned)sb * 64u + lane]);
      a0 = fmaf(ab, f.x, a0);
      a1 = fmaf(ab, f.y, a1);
    }
  }
  // reduce dsum over the 8 g-slots (bits 3..5 of lane), then fetch my head's denom
  dsum += __shfl_xor(dsum, 8, 64);
  dsum += __shfl_xor(dsum, 16, 64);
  dsum += __shfl_xor(dsum, 32, 64);
  float denom = __shfl(dsum, hf, 64);   // lane hf holds (g=0, h8=hf)
  float inv = 1.f / (denom + 1e-16f);
  hout[(size_t)node * 64 + lane] =
      __float22bfloat162_rn(make_float2(fmaxf(a0 * inv, 0.f), fmaxf(a1 * inv, 0.f)));
}

// ---------------- semantic attention via MFMA ----------------
#define KWS 136
#define NTILES ((NN + 63) / 64)
#define SEMGX 256

__global__ __launch_bounds__(256) void k_sem(const __hip_bfloat16* __restrict__ h0,
    const __hip_bfloat16* __restrict__ h1, const float* __restrict__ kw,
    const float* __restrict__ kb, float* __restrict__ ksum) {
  __shared__ short kwT[128 * KWS];
  __shared__ float red[4][128];
  const int tid = threadIdx.x;
  const int m = blockIdx.y;
  const short* __restrict__ hc = (const short*)(m ? h1 : h0);
  for (int l = tid; l < 128 * 128; l += 256) {
    int i = l >> 7, j = l & 127;   // kw[i][j] -> kwT[j][i]
    __hip_bfloat16 bv = __float2bfloat16(kw[l]);
    kwT[j * KWS + i] = *(short*)&bv;
  }
  const int lane = tid & 63;
  const int wave = tid >> 6;
  const int rowgrp = lane >> 4;
  const int lcol = lane & 15;
  float partial[8] = {};
  float kbv[8];
#pragma unroll
  for (int ct = 0; ct < 8; ct++) kbv[ct] = kb[ct * 16 + lcol];
  __syncthreads();
  for (int tile = blockIdx.x; tile < NTILES; tile += SEMGX) {
    int n0 = tile * 64 + wave * 16;
    int row = n0 + lcol;
    if (row >= NN) row = 0;
    const short* hr = hc + (size_t)row * 128 + rowgrp * 8;
    short8 afrag[4];
#pragma unroll
    for (int kc = 0; kc < 4; kc++) afrag[kc] = *(const short8*)(hr + kc * 32);
#pragma unroll
    for (int ct = 0; ct < 8; ct++) {
      f32x4 acc = {0.f, 0.f, 0.f, 0.f};
#pragma unroll
      for (int kc = 0; kc < 4; kc++) {
        short8 bfrag = *(const short8*)&kwT[(ct * 16 + lcol) * KWS + kc * 32 + rowgrp * 8];
        acc = __builtin_amdgcn_mfma_f32_16x16x32_bf16(afrag[kc], bfrag, acc, 0, 0, 0);
      }
#pragma unroll
      for (int r = 0; r < 4; r++) {
        int node = n0 + rowgrp * 4 + r;
        if (node < NN) partial[ct] += tanhf(acc[r] + kbv[ct]);
      }
    }
  }
#pragma unroll
  for (int ct = 0; ct < 8; ct++) {
    partial[ct] += __shfl_xor(partial[ct], 16, 64);
    partial[ct] += __shfl_xor(partial[ct], 32, 64);
  }
  if (lane < 16) {
#pragma unroll
    for (int ct = 0; ct < 8; ct++) red[wave][ct * 16 + lane] = partial[ct];
  }
  __syncthreads();
  if (tid < 128) {
    float s = red[0][tid] + red[1][tid] + red[2][tid] + red[3][tid];
    atomicAdd(&ksum[m * 128 + tid], s);
  }
}

// ---------------- softmax over 2 metapath logits ----------------
__global__ void k_attn(const float* __restrict__ ksum, const float* __restrict__ q,
                       float* __restrict__ attn) {
  __shared__ float red0[128], red1[128];
  int t = threadIdx.x;
  float qv = q[t];
  red0[t] = ksum[t] * qv;
  red1[t] = ksum[128 + t] * qv;
  __syncthreads();
  for (int off = 64; off > 0; off >>= 1) {
    if (t < off) {
      red0[t] += red0[t + off];
      red1[t] += red1[t + off];
    }
    __syncthreads();
  }
  if (t == 0) {
    float l0 = red0[0] / (float)NN, l1 = red1[0] / (float)NN;
    float mx = fmaxf(l0, l1);
    float e0 = __expf(l0 - mx), e1 = __expf(l1 - mx);
    float s = e0 + e1;
    attn[0] = e0 / s;
    attn[1] = e1 / s;
  }
}

// ---------------- fuse + output head ----------------
__global__ __launch_bounds__(256) void k_final(const __hip_bfloat162* __restrict__ h0,
    const __hip_bfloat162* __restrict__ h1, const float* __restrict__ lw,
    const float* __restrict__ lb, const float* __restrict__ attn,
    float* __restrict__ out) {
  const int lane = threadIdx.x & 63;
  const int node = blockIdx.x * 4 + (threadIdx.x >> 6);
  if (node >= NN) return;
  float a0 = attn[0], a1 = attn[1];
  float2 v0 = __bfloat1622float2(h0[(size_t)node * 64 + lane]);
  float2 v1 = __bfloat1622float2(h1[(size_t)node * 64 + lane]);
  float f0 = a0 * v0.x + a1 * v1.x;
  float f1 = a0 * v0.y + a1 * v1.y;
  int i0 = 2 * lane;
  float p[4];
#pragma unroll
  for (int c = 0; c < 4; c++)
    p[c] = f0 * lw[i0 * 4 + c] + f1 * lw[(i0 + 1) * 4 + c];
#pragma unroll
  for (int off = 32; off > 0; off >>= 1) {
#pragma unroll
    for (int c = 0; c < 4; c++) p[c] += __shfl_down(p[c], off, 64);
  }
  if (lane == 0) {
#pragma unroll
    for (int c = 0; c < 4; c++) out[(size_t)node * 4 + c] = p[c] + lb[c];
  }
}

extern "C" void kernel_launch(void* const* d_in, const int* in_sizes, int n_in,
                              void* d_out, int out_size, void* d_ws, size_t ws_size,
                              hipStream_t stream) {
  const float* x      = (const float*)d_in[0];
  const int*   ei0    = (const int*)d_in[1];
  const int*   ei1    = (const int*)d_in[2];
  const float* proj_w = (const float*)d_in[3];
  const float* proj_b = (const float*)d_in[4];
  const float* a0s    = (const float*)d_in[5];
  const float* a0d    = (const float*)d_in[6];
  const float* a1s    = (const float*)d_in[7];
  const float* a1d    = (const float*)d_in[8];
  const float* klw    = (const float*)d_in[9];
  const float* klb    = (const float*)d_in[10];
  const float* q      = (const float*)d_in[11];
  const float* lw     = (const float*)d_in[12];
  const float* lb     = (const float*)d_in[13];
  float* out = (float*)d_out;

  char* ws = (char*)d_ws;
  size_t off = 0;
  auto alloc = [&](size_t bytes) -> void* {
    size_t o = (off + 255) & ~(size_t)255;
    off = o + bytes;
    return (void*)(ws + o);
  };
  __hip_bfloat162* xph = (__hip_bfloat162*)alloc((size_t)NN * 128 * 2);
  __hip_bfloat162* h0  = (__hip_bfloat162*)alloc((size_t)NN * 128 * 2);
  __hip_bfloat162* h1  = (__hip_bfloat162*)alloc((size_t)NN * 128 * 2);
  float* as0  = (float*)alloc((size_t)NN * 8 * 4);
  float* ad0  = (float*)alloc((size_t)NN * 8 * 4);
  float* as1  = (float*)alloc((size_t)NN * 8 * 4);
  float* ad1  = (float*)alloc((size_t)NN * 8 * 4);
  int* cnt    = (int*)alloc((size_t)2 * NN * 4);   // 800000 B (multiple of 256)
  float* ksum = (float*)alloc(256 * 4);            // contiguous after cnt
  int* gcur   = (int*)alloc(2 * 256 * 4);          // contiguous after ksum
  float* attn = (float*)alloc(256);
  int* csr    = (int*)alloc((size_t)2 * NN * CAP * 4);
  int* binned = (int*)alloc((size_t)2 * NB * CAPB * 4);

  // zero cnt + ksum + gcur in one shot (contiguous layout)
  hipMemsetAsync(cnt, 0, (size_t)2 * NN * 4 + 256 * 4 + 2 * 256 * 4, stream);

  k_proj<<<dim3(256), 256, 0, stream>>>(x, proj_w, proj_b, (__hip_bfloat16*)xph);
  k_alpha<<<dim3((NN + 3) / 4), 256, 0, stream>>>(xph, a0s, a0d, a1s, a1d,
                                                  as0, ad0, as1, ad1);
  k_bin<<<dim3((EE + EBLK - 1) / EBLK, 2), 256, 0, stream>>>(ei0, ei1, gcur, binned);
  k_build<<<dim3(NB, 2), 512, 0, stream>>>(gcur, binned, cnt, csr);
  k_aggr<<<dim3((NN + 3) / 4, 2), 256, 0, stream>>>(xph, as0, ad0, as1, ad1,
                                                    cnt, csr, h0, h1);
  k_sem<<<dim3(SEMGX, 2), 256, 0, stream>>>((const __hip_bfloat16*)h0,
                                            (const __hip_bfloat16*)h1, klw, klb, ksum);
  k_attn<<<dim3(1), 128, 0, stream>>>(ksum, q, attn);
  k_final<<<dim3((NN + 3) / 4), 256, 0, stream>>>(h0, h1, lw, lb, attn, out);
}

// Round 8
// 526.856 us; speedup vs baseline: 1.1731x; 1.1731x over previous
//
#include <hip/hip_runtime.h>
#include <hip/hip_bf16.h>

#define NN 100000
#define EE 1600000
#define HID 128
#define NEG 0.2f
#define CAP 64     // fixed CSR capacity per node (avg deg 16, P(deg>64) ~ 1e-19)
#define BSH 9      // coarse bucket = dst >> 9 (512 nodes/bucket)
#define NB 196     // ceil(NN / 512)
#define CAPB 9216  // per-bucket edge capacity (mean 8192, sigma~90 -> 11 sigma)
#define EBLK 4096  // edges per k_bin block (782 blocks -> ~12 waves/CU)

typedef __attribute__((ext_vector_type(8))) short short8;
typedef __attribute__((ext_vector_type(4))) float f32x4;

// ---------------- projection GEMM via MFMA: xph = bf16(x @ proj_w + b) --------
#define PWS 264    // wT LDS stride in bf16 elems (528 B, 16B-aligned rows)
#define PNT ((NN + 15) / 16)   // 6250 row-tiles

__global__ __launch_bounds__(256) void k_proj(const float* __restrict__ x,
    const float* __restrict__ w, const float* __restrict__ bias,
    __hip_bfloat16* __restrict__ xph) {
  __shared__ short wT[128 * PWS];   // w^T as bf16, [n][k]
  const int tid = threadIdx.x;
  for (int l = tid; l < 256 * 128; l += 256) {
    int k = l >> 7, n = l & 127;
    __hip_bfloat16 bv = __float2bfloat16(w[l]);
    wT[n * PWS + k] = *(short*)&bv;
  }
  const int lane = tid & 63, wave = tid >> 6;
  const int rowgrp = lane >> 4, lcol = lane & 15;
  float bv[8];
#pragma unroll
  for (int ct = 0; ct < 8; ct++) bv[ct] = bias[ct * 16 + lcol];
  __syncthreads();
  for (int tile = blockIdx.x * 4 + wave; tile < PNT; tile += gridDim.x * 4) {
    const int r0 = tile * 16;
    int row = r0 + lcol;
    if (row >= NN) row = NN - 1;   // clamped load; stores guarded below
    const float* xr = x + (size_t)row * 256 + rowgrp * 8;
    short8 af[8];
#pragma unroll
    for (int kc = 0; kc < 8; kc++) {
      float4 u0 = *(const float4*)(xr + kc * 32);
      float4 u1 = *(const float4*)(xr + kc * 32 + 4);
      union { short8 v; __hip_bfloat162 h[4]; } u;
      u.h[0] = __float22bfloat162_rn(make_float2(u0.x, u0.y));
      u.h[1] = __float22bfloat162_rn(make_float2(u0.z, u0.w));
      u.h[2] = __float22bfloat162_rn(make_float2(u1.x, u1.y));
      u.h[3] = __float22bfloat162_rn(make_float2(u1.z, u1.w));
      af[kc] = u.v;
    }
#pragma unroll
    for (int ct = 0; ct < 8; ct++) {
      f32x4 acc = {0.f, 0.f, 0.f, 0.f};
#pragma unroll
      for (int kc = 0; kc < 8; kc++) {
        short8 bf = *(const short8*)&wT[(ct * 16 + lcol) * PWS + kc * 32 + rowgrp * 8];
        acc = __builtin_amdgcn_mfma_f32_16x16x32_bf16(af[kc], bf, acc, 0, 0, 0);
      }
#pragma unroll
      for (int r = 0; r < 4; r++) {
        int orow = r0 + rowgrp * 4 + r;   // C/D: row = (lane>>4)*4 + reg
        if (orow < NN) {
          __hip_bfloat16 ob = __float2bfloat16(acc[r] + bv[ct]);
          ((short*)xph)[(size_t)orow * 128 + ct * 16 + lcol] = *(short*)&ob;
        }
      }
    }
  }
}

// ---------------- per-node attention logits (bf16 xph) ----------------
__global__ __launch_bounds__(256) void k_alpha(const __hip_bfloat162* __restrict__ xph,
    const float* __restrict__ a0s, const float* __restrict__ a0d,
    const float* __restrict__ a1s, const float* __restrict__ a1d,
    float* __restrict__ as0, float* __restrict__ ad0,
    float* __restrict__ as1, float* __restrict__ ad1) {
  const int lane = threadIdx.x & 63;
  const int node = blockIdx.x * 4 + (threadIdx.x >> 6);
  if (node >= NN) return;
  float2 v = __bfloat1622float2(xph[(size_t)node * 64 + lane]);
  int i0 = 2 * lane;
  float p0 = v.x * a0s[i0] + v.y * a0s[i0 + 1];
  float p1 = v.x * a0d[i0] + v.y * a0d[i0 + 1];
  float p2 = v.x * a1s[i0] + v.y * a1s[i0 + 1];
  float p3 = v.x * a1d[i0] + v.y * a1d[i0 + 1];
#pragma unroll
  for (int off = 1; off < 8; off <<= 1) {
    p0 += __shfl_xor(p0, off, 64);
    p1 += __shfl_xor(p1, off, 64);
    p2 += __shfl_xor(p2, off, 64);
    p3 += __shfl_xor(p3, off, 64);
  }
  if ((lane & 7) == 0) {
    int h = lane >> 3;
    as0[node * 8 + h] = p0;
    ad0[node * 8 + h] = p1;
    as1[node * 8 + h] = p2;
    ad1[node * 8 + h] = p3;
  }
}

// ---------------- phase A: bin edges by coarse dst bucket ----------------
__global__ __launch_bounds__(256) void k_bin(const int* __restrict__ ei0,
    const int* __restrict__ ei1, int* __restrict__ gcur, int* __restrict__ binned) {
  const int p = blockIdx.y;
  const int* __restrict__ ei = p ? ei1 : ei0;
  const int* __restrict__ src = ei;
  const int* __restrict__ dst = ei + EE;
  int* __restrict__ gc = gcur + p * 256;
  int* __restrict__ bn = binned + (size_t)p * NB * CAPB;
  __shared__ int cntL[NB], baseL[NB], posL[NB];
  const int t = threadIdx.x;
  const int e0 = blockIdx.x * EBLK;
  const int e1 = min(e0 + EBLK, EE);
  for (int i = t; i < NB; i += 256) { cntL[i] = 0; posL[i] = 0; }
  __syncthreads();
  for (int e = e0 + t; e < e1; e += 256)
    atomicAdd(&cntL[dst[e] >> BSH], 1);
  __syncthreads();
  for (int i = t; i < NB; i += 256)
    baseL[i] = atomicAdd(&gc[i], cntL[i]);
  __syncthreads();
  for (int e = e0 + t; e < e1; e += 256) {
    int d = dst[e];
    int b = d >> BSH;
    int off = baseL[b] + atomicAdd(&posL[b], 1);
    if (off < CAPB) bn[b * CAPB + off] = (src[e] << BSH) | (d & 511);
  }
}

// ---------------- phase B: bucket -> fixed-capacity CSR ----------------
__global__ __launch_bounds__(512) void k_build(const int* __restrict__ gcur,
    const int* __restrict__ binned, int* __restrict__ cnt, int* __restrict__ csr) {
  const int p = blockIdx.y, b = blockIdx.x, t = threadIdx.x;
  const int* __restrict__ bn = binned + (size_t)p * NB * CAPB + (size_t)b * CAPB;
  const int n = min(gcur[p * 256 + b], CAPB);
  int* __restrict__ cs = csr + (size_t)p * NN * CAP;
  __shared__ int lc[512];
  lc[t] = 0;
  __syncthreads();
  const int node0 = b << BSH;
  for (int i = t; i < n; i += 512) {
    int v = bn[i];
    int ln = v & 511;
    int off = atomicAdd(&lc[ln], 1);
    if (off < CAP) cs[(size_t)(node0 + ln) * CAP + off] = v >> BSH;
  }
  __syncthreads();
  int n0 = node0 + t;
  if (n0 < NN) cnt[p * NN + n0] = lc[t];
}

// ---------------- GAT aggregation: single-pass, one wave per dst node ----------
// (round-6 form, proven 158 us. Do NOT route the src index or alpha through
// __shfl/ds_bpermute here: r7 tried it, VALUBusy fell 71->32% but the LDS-pipe
// hop in the gather-address chain made the kernel latency-bound, 158->252 us.)
#define LRELU(t) ((t) > 0.f ? (t) : NEG * (t))

#define EDGE_BODY(sv)                                      \
  {                                                        \
    unsigned s = (unsigned)(sv);                           \
    float t = asrc[s * 8u + h];                            \
    __hip_bfloat162 v = xph[s * 64u + lane];               \
    float al = __expf(LRELU(t + ad));                      \
    denom += al;                                           \
    float2 f = __bfloat1622float2(v);                      \
    a0 = fmaf(al, f.x, a0);                                \
    a1 = fmaf(al, f.y, a1);                                \
  }

__global__ __launch_bounds__(256) void k_aggr(const __hip_bfloat162* __restrict__ xph,
    const float* __restrict__ as0, const float* __restrict__ ad0,
    const float* __restrict__ as1, const float* __restrict__ ad1,
    const int* __restrict__ cnt, const int* __restrict__ csr,
    __hip_bfloat162* __restrict__ h0, __hip_bfloat162* __restrict__ h1) {
  const int p = blockIdx.y;
  const unsigned lane = threadIdx.x & 63;
  const int node = blockIdx.x * 4 + (threadIdx.x >> 6);
  if (node >= NN) return;
  const float* __restrict__ asrc = p ? as1 : as0;
  const float* __restrict__ adst = p ? ad1 : ad0;
  const int* __restrict__ cs = csr + ((size_t)p * NN + node) * CAP;
  __hip_bfloat162* __restrict__ hout = p ? h1 : h0;
  const unsigned h = lane >> 3;
  const float ad = adst[(unsigned)node * 8u + h];
  const int deg = min(cnt[p * NN + node], CAP);

  float denom = 1e-16f, a0 = 0.f, a1 = 0.f;
  int e = 0;
  for (; e + 8 <= deg; e += 8) {
    int4 q0 = *(const int4*)&cs[e];       // wave-uniform, 16B-aligned (CAP layout)
    int4 q1 = *(const int4*)&cs[e + 4];
    EDGE_BODY(q0.x) EDGE_BODY(q0.y) EDGE_BODY(q0.z) EDGE_BODY(q0.w)
    EDGE_BODY(q1.x) EDGE_BODY(q1.y) EDGE_BODY(q1.z) EDGE_BODY(q1.w)
  }
  for (; e + 4 <= deg; e += 4) {
    int4 q0 = *(const int4*)&cs[e];
    EDGE_BODY(q0.x) EDGE_BODY(q0.y) EDGE_BODY(q0.z) EDGE_BODY(q0.w)
  }
  for (; e < deg; e++) EDGE_BODY(cs[e])
  float inv = 1.f / denom;
  hout[(size_t)node * 64 + lane] =
      __float22bfloat162_rn(make_float2(fmaxf(a0 * inv, 0.f), fmaxf(a1 * inv, 0.f)));
}

// ---------------- semantic attention via MFMA ----------------
#define KWS 136
#define NTILES ((NN + 63) / 64)
#define SEMGX 256

__global__ __launch_bounds__(256) void k_sem(const __hip_bfloat16* __restrict__ h0,
    const __hip_bfloat16* __restrict__ h1, const float* __restrict__ kw,
    const float* __restrict__ kb, float* __restrict__ ksum) {
  __shared__ short kwT[128 * KWS];
  __shared__ float red[4][128];
  const int tid = threadIdx.x;
  const int m = blockIdx.y;
  const short* __restrict__ hc = (const short*)(m ? h1 : h0);
  for (int l = tid; l < 128 * 128; l += 256) {
    int i = l >> 7, j = l & 127;   // kw[i][j] -> kwT[j][i]
    __hip_bfloat16 bv = __float2bfloat16(kw[l]);
    kwT[j * KWS + i] = *(short*)&bv;
  }
  const int lane = tid & 63;
  const int wave = tid >> 6;
  const int rowgrp = lane >> 4;
  const int lcol = lane & 15;
  float partial[8] = {};
  float kbv[8];
#pragma unroll
  for (int ct = 0; ct < 8; ct++) kbv[ct] = kb[ct * 16 + lcol];
  __syncthreads();
  for (int tile = blockIdx.x; tile < NTILES; tile += SEMGX) {
    int n0 = tile * 64 + wave * 16;
    int row = n0 + lcol;
    if (row >= NN) row = 0;
    const short* hr = hc + (size_t)row * 128 + rowgrp * 8;
    short8 afrag[4];
#pragma unroll
    for (int kc = 0; kc < 4; kc++) afrag[kc] = *(const short8*)(hr + kc * 32);
#pragma unroll
    for (int ct = 0; ct < 8; ct++) {
      f32x4 acc = {0.f, 0.f, 0.f, 0.f};
#pragma unroll
      for (int kc = 0; kc < 4; kc++) {
        short8 bfrag = *(const short8*)&kwT[(ct * 16 + lcol) * KWS + kc * 32 + rowgrp * 8];
        acc = __builtin_amdgcn_mfma_f32_16x16x32_bf16(afrag[kc], bfrag, acc, 0, 0, 0);
      }
#pragma unroll
      for (int r = 0; r < 4; r++) {
        int node = n0 + rowgrp * 4 + r;
        if (node < NN) partial[ct] += tanhf(acc[r] + kbv[ct]);
      }
    }
  }
#pragma unroll
  for (int ct = 0; ct < 8; ct++) {
    partial[ct] += __shfl_xor(partial[ct], 16, 64);
    partial[ct] += __shfl_xor(partial[ct], 32, 64);
  }
  if (lane < 16) {
#pragma unroll
    for (int ct = 0; ct < 8; ct++) red[wave][ct * 16 + lane] = partial[ct];
  }
  __syncthreads();
  if (tid < 128) {
    float s = red[0][tid] + red[1][tid] + red[2][tid] + red[3][tid];
    atomicAdd(&ksum[m * 128 + tid], s);
  }
}

// ---------------- softmax over 2 metapath logits ----------------
__global__ void k_attn(const float* __restrict__ ksum, const float* __restrict__ q,
                       float* __restrict__ attn) {
  __shared__ float red0[128], red1[128];
  int t = threadIdx.x;
  float qv = q[t];
  red0[t] = ksum[t] * qv;
  red1[t] = ksum[128 + t] * qv;
  __syncthreads();
  for (int off = 64; off > 0; off >>= 1) {
    if (t < off) {
      red0[t] += red0[t + off];
      red1[t] += red1[t + off];
    }
    __syncthreads();
  }
  if (t == 0) {
    float l0 = red0[0] / (float)NN, l1 = red1[0] / (float)NN;
    float mx = fmaxf(l0, l1);
    float e0 = __expf(l0 - mx), e1 = __expf(l1 - mx);
    float s = e0 + e1;
    attn[0] = e0 / s;
    attn[1] = e1 / s;
  }
}

// ---------------- fuse + output head ----------------
__global__ __launch_bounds__(256) void k_final(const __hip_bfloat162* __restrict__ h0,
    const __hip_bfloat162* __restrict__ h1, const float* __restrict__ lw,
    const float* __restrict__ lb, const float* __restrict__ attn,
    float* __restrict__ out) {
  const int lane = threadIdx.x & 63;
  const int node = blockIdx.x * 4 + (threadIdx.x >> 6);
  if (node >= NN) return;
  float a0 = attn[0], a1 = attn[1];
  float2 v0 = __bfloat1622float2(h0[(size_t)node * 64 + lane]);
  float2 v1 = __bfloat1622float2(h1[(size_t)node * 64 + lane]);
  float f0 = a0 * v0.x + a1 * v1.x;
  float f1 = a0 * v0.y + a1 * v1.y;
  int i0 = 2 * lane;
  float p[4];
#pragma unroll
  for (int c = 0; c < 4; c++)
    p[c] = f0 * lw[i0 * 4 + c] + f1 * lw[(i0 + 1) * 4 + c];
#pragma unroll
  for (int off = 32; off > 0; off >>= 1) {
#pragma unroll
    for (int c = 0; c < 4; c++) p[c] += __shfl_down(p[c], off, 64);
  }
  if (lane == 0) {
#pragma unroll
    for (int c = 0; c < 4; c++) out[(size_t)node * 4 + c] = p[c] + lb[c];
  }
}

extern "C" void kernel_launch(void* const* d_in, const int* in_sizes, int n_in,
                              void* d_out, int out_size, void* d_ws, size_t ws_size,
                              hipStream_t stream) {
  const float* x      = (const float*)d_in[0];
  const int*   ei0    = (const int*)d_in[1];
  const int*   ei1    = (const int*)d_in[2];
  const float* proj_w = (const float*)d_in[3];
  const float* proj_b = (const float*)d_in[4];
  const float* a0s    = (const float*)d_in[5];
  const float* a0d    = (const float*)d_in[6];
  const float* a1s    = (const float*)d_in[7];
  const float* a1d    = (const float*)d_in[8];
  const float* klw    = (const float*)d_in[9];
  const float* klb    = (const float*)d_in[10];
  const float* q      = (const float*)d_in[11];
  const float* lw     = (const float*)d_in[12];
  const float* lb     = (const float*)d_in[13];
  float* out = (float*)d_out;

  char* ws = (char*)d_ws;
  size_t off = 0;
  auto alloc = [&](size_t bytes) -> void* {
    size_t o = (off + 255) & ~(size_t)255;
    off = o + bytes;
    return (void*)(ws + o);
  };
  __hip_bfloat162* xph = (__hip_bfloat162*)alloc((size_t)NN * 128 * 2);
  __hip_bfloat162* h0  = (__hip_bfloat162*)alloc((size_t)NN * 128 * 2);
  __hip_bfloat162* h1  = (__hip_bfloat162*)alloc((size_t)NN * 128 * 2);
  float* as0  = (float*)alloc((size_t)NN * 8 * 4);
  float* ad0  = (float*)alloc((size_t)NN * 8 * 4);
  float* as1  = (float*)alloc((size_t)NN * 8 * 4);
  float* ad1  = (float*)alloc((size_t)NN * 8 * 4);
  int* cnt    = (int*)alloc((size_t)2 * NN * 4);   // 800000 B (multiple of 256)
  float* ksum = (float*)alloc(256 * 4);            // contiguous after cnt
  int* gcur   = (int*)alloc(2 * 256 * 4);          // contiguous after ksum
  float* attn = (float*)alloc(256);
  int* csr    = (int*)alloc((size_t)2 * NN * CAP * 4);
  int* binned = (int*)alloc((size_t)2 * NB * CAPB * 4);

  // zero cnt + ksum + gcur in one shot (contiguous layout)
  hipMemsetAsync(cnt, 0, (size_t)2 * NN * 4 + 256 * 4 + 2 * 256 * 4, stream);

  k_proj<<<dim3(256), 256, 0, stream>>>(x, proj_w, proj_b, (__hip_bfloat16*)xph);
  k_alpha<<<dim3((NN + 3) / 4), 256, 0, stream>>>(xph, a0s, a0d, a1s, a1d,
                                                  as0, ad0, as1, ad1);
  k_bin<<<dim3((EE + EBLK - 1) / EBLK, 2), 256, 0, stream>>>(ei0, ei1, gcur, binned);
  k_build<<<dim3(NB, 2), 512, 0, stream>>>(gcur, binned, cnt, csr);
  k_aggr<<<dim3((NN + 3) / 4, 2), 256, 0, stream>>>(xph, as0, ad0, as1, ad1,
                                                    cnt, csr, h0, h1);
  k_sem<<<dim3(SEMGX, 2), 256, 0, stream>>>((const __hip_bfloat16*)h0,
                                            (const __hip_bfloat16*)h1, klw, klb, ksum);
  k_attn<<<dim3(1), 128, 0, stream>>>(ksum, q, attn);
  k_final<<<dim3((NN + 3) / 4), 256, 0, stream>>>(h0, h1, lw, lb, attn, out);
}